// Round 5
// baseline (1017.275 us; speedup 1.0000x reference)
//
#include <hip/hip_runtime.h>
#include <cstdint>
#include <cstddef>

#define D 1024
#define BATCH 16384
#define NLAYERS 18
#define RR 32

typedef __attribute__((ext_vector_type(8))) __bf16 bf16x8;
typedef __attribute__((ext_vector_type(4))) float f32x4;
typedef __attribute__((ext_vector_type(16))) float f32x16;
typedef __attribute__((address_space(3))) void lds_void_t;
typedef __attribute__((address_space(1))) void gmem_void_t;

__device__ __forceinline__ unsigned short f2bf(float f) {
    unsigned int b = __builtin_bit_cast(unsigned int, f);
    b += 0x7fffu + ((b >> 16) & 1u);
    return (unsigned short)(b >> 16);
}
__device__ __forceinline__ float bf2f(unsigned short u) {
    return __builtin_bit_cast(float, (unsigned int)u << 16);
}

// ---------------------------------------------------------------------------
// prep, two-phase: phase 1 computes the LoRA tile with broadcast la_s reads
// (lane->row mapping) into lo_s (bf16); phase 2 re-maps to the coalesced
// layout (32 lanes = 1KB contiguous per q row) for dequant+add+store.
// R3's single-phase lane->row mapping made q reads a 64-row scatter
// (FETCH 48->148MB); this keeps broadcast FMA AND coalesced q.
// ---------------------------------------------------------------------------
__global__ __launch_bounds__(256) void prep_weights(
    const int* __restrict__ q, const float* __restrict__ scales,
    const float* __restrict__ la, const float* __restrict__ lb,
    unsigned short* __restrict__ weff) {
    __shared__ float la_s[32][260];
    __shared__ float lb_s[64][33];
    __shared__ unsigned short lo_s[64][264];   // 528B rows (33x16B, odd slots)
    const int b = blockIdx.x;            // 18*16*4
    const int li = b >> 6;
    const int o0 = ((b >> 2) & 15) << 6;
    const int i0 = (b & 3) << 8;
    const int t = threadIdx.x;

    {   // lb tile: 64 rows x 32 r
        const float* src = lb + ((size_t)li * D + o0) * RR;
        for (int i = t; i < 512; i += 256) {
            float4 v = ((const float4*)src)[i];
            const int o = i >> 3, c = (i & 7) << 2;
            lb_s[o][c] = v.x; lb_s[o][c + 1] = v.y; lb_s[o][c + 2] = v.z; lb_s[o][c + 3] = v.w;
        }
    }
    {   // la tile: 32 r x 256 cols
        for (int i = t; i < 2048; i += 256) {
            const int r = i >> 6, c = (i & 63) << 2;
            float4 v = *(const float4*)(la + ((size_t)li * RR + r) * D + i0 + c);
            la_s[r][c] = v.x; la_s[r][c + 1] = v.y; la_s[r][c + 2] = v.z; la_s[r][c + 3] = v.w;
        }
    }
    __syncthreads();

    // ---- phase 1: lora tile -> lo_s (bf16, already x LORA_SCALE) ----
    {
        const int ol = t & 63;               // lane -> row (lb stride-33, free)
        const int ibase = (t >> 6) << 6;     // wave -> 64-col stripe (broadcast la)
        float lbr[32];
#pragma unroll
        for (int r = 0; r < 32; ++r) lbr[r] = lb_s[ol][r];
#pragma unroll 1
        for (int iter = 0; iter < 8; ++iter) {
            const int i8 = ibase + (iter << 3);
            float acc[8] = {0.f, 0.f, 0.f, 0.f, 0.f, 0.f, 0.f, 0.f};
#pragma unroll 16
            for (int r = 0; r < 32; ++r) {
                float4 u0 = *(const float4*)&la_s[r][i8];       // wave-uniform
                float4 u1 = *(const float4*)&la_s[r][i8 + 4];
                const float bv = lbr[r];
                acc[0] += bv * u0.x; acc[1] += bv * u0.y; acc[2] += bv * u0.z; acc[3] += bv * u0.w;
                acc[4] += bv * u1.x; acc[5] += bv * u1.y; acc[6] += bv * u1.z; acc[7] += bv * u1.w;
            }
            union { unsigned short us[8]; int4 v; } u;
#pragma unroll
            for (int j = 0; j < 8; ++j) u.us[j] = f2bf(4.0f * acc[j]);
            *(int4*)&lo_s[ol][i8] = u.v;
        }
    }
    __syncthreads();

    // ---- phase 2: coalesced dequant + add ----
#pragma unroll 1
    for (int iter = 0; iter < 8; ++iter) {
        const int cidx = t + (iter << 8);     // 0..2047
        const int row = cidx >> 5;            // 0..63
        const int i8 = (cidx & 31) << 3;      // 0..248
        const size_t grow = (size_t)li * D + o0 + row;
        const int col = i0 + i8;
        const float s = scales[grow * (D / 16) + (col >> 4)];
        const int* qp = q + grow * D + col;
        int4 q0 = ((const int4*)qp)[0], q1 = ((const int4*)qp)[1];
        union { unsigned short us[8]; int4 v; } lo;
        lo.v = *(const int4*)&lo_s[row][i8];
        int qa[8] = {q0.x, q0.y, q0.z, q0.w, q1.x, q1.y, q1.z, q1.w};
        union { unsigned short us[8]; int4 v; } u;
        const float c = 2.0f / 15.0f;
#pragma unroll
        for (int j = 0; j < 8; ++j)
            u.us[j] = f2bf(((float)qa[j] * c - 1.0f) * s + bf2f(lo.us[j]));
        *(int4*)(weff + grow * D + col) = u.v;
    }
}

// h = x (f32); xb = bf16(x)
__global__ __launch_bounds__(256) void init_h(const float* __restrict__ x,
                                              float* __restrict__ h,
                                              unsigned short* __restrict__ xb) {
    const size_t i = (size_t)blockIdx.x * 256 + threadIdx.x;
    float4 v = ((const float4*)x)[i];
    ((float4*)h)[i] = v;
    ushort4 u;
    u.x = f2bf(v.x); u.y = f2bf(v.y); u.z = f2bf(v.z); u.w = f2bf(v.w);
    ((ushort4*)xb)[i] = u;
}

// ---------------------------------------------------------------------------
// 256x256 tile GEMM, 8 waves (2Mx4N), 32x32x16 bf16 MFMA (2495 TF ceiling
// vs 2075 for 16x16), BK=32 half-steps, 4-slot LDS ring, depth-3 counted-
// vmcnt pipeline (vmcnt(8) once per half-step, never 0 in main loop).
// LDS layout chunk-transposed: [chunk c=k16B][row][16B] so a 32-row
// fragment read is a dense contiguous 512B per half-wave -> conflict-free
// (row-major 64B rows would be an irreducible 4-way). No swizzle needed;
// global_load_lds dest linear per wave (chunk=wid&3, rowgrp=(wid>>2)*2+i).
// A/B frag: row/col = l&31, k = (l>>5)*8+j. C/D: col=lane&31,
// row=(reg&3)+8*(reg>>2)+4*(lane>>5)  [m74/m101].
// mode 0: outb = bf16(relu(v));  mode 1: outb = bf16(v).
// ---------------------------------------------------------------------------
#define SBAR() do { asm volatile("" ::: "memory"); __builtin_amdgcn_s_barrier(); asm volatile("" ::: "memory"); } while (0)

__global__ __launch_bounds__(512, 2) void gemm256(
    const unsigned short* __restrict__ xb, const unsigned short* __restrict__ w,
    const float* __restrict__ bias,
    unsigned short* __restrict__ outb, int mode) {
    __shared__ __align__(16) char smem[131072];
    const int tid = threadIdx.x;
    const int wid = tid >> 6, lane = tid & 63;
    // XCD-chunked swizzle: 256 blocks = 1/CU; XCD k gets m-panels [8k,8k+8)
    const int bid = blockIdx.x + (blockIdx.y << 2);
    const int xcd = bid & 7, slot = bid >> 3;
    const int m0 = ((xcd << 3) + (slot >> 2)) << 8;
    const int n0 = (slot & 3) << 8;
    const int l31 = lane & 31, khalf = lane >> 5;
    const int wrow = (wid >> 2) << 7;   // 0 / 128
    const int wcol = (wid & 3) << 6;    // 0..192

    f32x16 acc[4][2];
#pragma unroll
    for (int i = 0; i < 4; ++i)
#pragma unroll
        for (int j = 0; j < 2; ++j) acc[i][j] = 0.0f;

    const int sc_ = wid & 3;                 // this wave's staging chunk
    const int sg_ = (wid >> 2) << 1;         // this wave's base row-group

#define STAGE_A(hs)                                                            \
    do {                                                                       \
        char* base_ = smem + ((hs) & 3) * 32768;                               \
        const int k0_ = ((hs) << 5) + (sc_ << 3);                              \
        _Pragma("unroll")                                                      \
        for (int i_ = 0; i_ < 2; ++i_) {                                       \
            const int row_ = ((sg_ + i_) << 6) + lane;                         \
            const unsigned short* ga_ = xb + (size_t)(m0 + row_) * D + k0_;    \
            char* dst_ = base_ + (sc_ << 12) + ((sg_ + i_) << 10);             \
            __builtin_amdgcn_global_load_lds((const gmem_void_t*)ga_, (lds_void_t*)dst_, 16, 0, 0); \
        }                                                                      \
    } while (0)

#define STAGE_B(hs)                                                            \
    do {                                                                       \
        char* base_ = smem + ((hs) & 3) * 32768 + 16384;                       \
        const int k0_ = ((hs) << 5) + (sc_ << 3);                              \
        _Pragma("unroll")                                                      \
        for (int i_ = 0; i_ < 2; ++i_) {                                       \
            const int row_ = ((sg_ + i_) << 6) + lane;                         \
            const unsigned short* gb_ = w + (size_t)(n0 + row_) * D + k0_;     \
            char* dst_ = base_ + (sc_ << 12) + ((sg_ + i_) << 10);             \
            __builtin_amdgcn_global_load_lds((const gmem_void_t*)gb_, (lds_void_t*)dst_, 16, 0, 0); \
        }                                                                      \
    } while (0)

    STAGE_A(0); STAGE_B(0);
    STAGE_A(1); STAGE_B(1);
    STAGE_A(2); STAGE_B(2);
    asm volatile("s_waitcnt vmcnt(8)" ::: "memory");   // slot 0 landed
    SBAR();

    for (int h = 0; h < 32; ++h) {
        const char* sA = smem + (h & 3) * 32768;
        const char* sB = sA + 16384;
        bf16x8 a[4], b[2];
        // ---- phase A (kk=0, chunk c = khalf) ----
        {
            const int rc = khalf << 12;
#pragma unroll
            for (int f = 0; f < 4; ++f)
                a[f] = *(const bf16x8*)(sA + rc + ((wrow + (f << 5) + l31) << 4));
#pragma unroll
            for (int g = 0; g < 2; ++g)
                b[g] = *(const bf16x8*)(sB + rc + ((wcol + (g << 5) + l31) << 4));
        }
        if (h < 29) STAGE_A(h + 3);
        SBAR();
        asm volatile("s_waitcnt lgkmcnt(0)" ::: "memory");
        __builtin_amdgcn_s_setprio(1);
#pragma unroll
        for (int mi = 0; mi < 4; ++mi)
#pragma unroll
            for (int ni = 0; ni < 2; ++ni)
                acc[mi][ni] = __builtin_amdgcn_mfma_f32_32x32x16_bf16(
                    a[mi], b[ni], acc[mi][ni], 0, 0, 0);
        __builtin_amdgcn_s_setprio(0);
        SBAR();
        // ---- phase B (kk=1, chunk c = khalf+2) ----
        {
            const int rc = (khalf + 2) << 12;
#pragma unroll
            for (int f = 0; f < 4; ++f)
                a[f] = *(const bf16x8*)(sA + rc + ((wrow + (f << 5) + l31) << 4));
#pragma unroll
            for (int g = 0; g < 2; ++g)
                b[g] = *(const bf16x8*)(sB + rc + ((wcol + (g << 5) + l31) << 4));
        }
        if (h < 29) {
            STAGE_B(h + 3);
            asm volatile("s_waitcnt vmcnt(8)" ::: "memory");  // slot h+1 landed
        } else if (h == 29) {
            asm volatile("s_waitcnt vmcnt(4)" ::: "memory");
        } else if (h == 30) {
            asm volatile("s_waitcnt vmcnt(0)" ::: "memory");
        }
        SBAR();
        asm volatile("s_waitcnt lgkmcnt(0)" ::: "memory");
        __builtin_amdgcn_s_setprio(1);
#pragma unroll
        for (int mi = 0; mi < 4; ++mi)
#pragma unroll
            for (int ni = 0; ni < 2; ++ni)
                acc[mi][ni] = __builtin_amdgcn_mfma_f32_32x32x16_bf16(
                    a[mi], b[ni], acc[mi][ni], 0, 0, 0);
        __builtin_amdgcn_s_setprio(0);
        SBAR();
    }

    // epilogue: 32x32 C/D: col = lane&31, row = (reg&3)+8*(reg>>2)+4*khalf
    const int colbase = n0 + wcol + l31;
    const float bv0 = bias[colbase];
    const float bv1 = bias[colbase + 32];
#pragma unroll
    for (int mi = 0; mi < 4; ++mi) {
        const int rbase = m0 + wrow + (mi << 5) + (khalf << 2);
#pragma unroll
        for (int ni = 0; ni < 2; ++ni) {
            const float bv = ni ? bv1 : bv0;
            const int col = colbase + (ni << 5);
#pragma unroll
            for (int reg = 0; reg < 16; ++reg) {
                const int row = rbase + (reg & 3) + ((reg >> 2) << 3);
                float v = acc[mi][ni][reg] + bv;
                if (mode == 0) v = v > 0.0f ? v : 0.0f;
                outb[(size_t)row * D + col] = f2bf(v);
            }
        }
    }
}

// h = LN(h + v) in place; xb = bf16(result)
__global__ __launch_bounds__(256) void resid_ln_v(
    float* __restrict__ h, const unsigned short* __restrict__ vb,
    unsigned short* __restrict__ xb,
    const float* __restrict__ gamma, const float* __restrict__ beta) {
    const int row = blockIdx.x;
    const int t = threadIdx.x;
    float* hr = h + (size_t)row * D;
    float4 v = ((float4*)hr)[t];
    ushort4 vv = ((const ushort4*)(vb + (size_t)row * D))[t];
    v.x += bf2f(vv.x); v.y += bf2f(vv.y); v.z += bf2f(vv.z); v.w += bf2f(vv.w);
    float s = v.x + v.y + v.z + v.w;
    float s2 = v.x * v.x + v.y * v.y + v.z * v.z + v.w * v.w;
#pragma unroll
    for (int off = 32; off > 0; off >>= 1) {
        s += __shfl_down(s, off);
        s2 += __shfl_down(s2, off);
    }
    __shared__ float red[8];
    const int wid = t >> 6, lane = t & 63;
    if (lane == 0) { red[wid] = s; red[wid + 4] = s2; }
    __syncthreads();
    s = red[0] + red[1] + red[2] + red[3];
    s2 = red[4] + red[5] + red[6] + red[7];
    const float mu = s * (1.0f / D);
    const float var = s2 * (1.0f / D) - mu * mu;
    const float rs = rsqrtf(var + 1e-5f);
    float4 g = ((const float4*)gamma)[t];
    float4 b = ((const float4*)beta)[t];
    float4 o;
    o.x = (v.x - mu) * rs * g.x + b.x;
    o.y = (v.y - mu) * rs * g.y + b.y;
    o.z = (v.z - mu) * rs * g.z + b.z;
    o.w = (v.w - mu) * rs * g.w + b.w;
    ((float4*)hr)[t] = o;
    ushort4 u;
    u.x = f2bf(o.x); u.y = f2bf(o.y); u.z = f2bf(o.z); u.w = f2bf(o.w);
    ((ushort4*)(xb + (size_t)row * D))[t] = u;
}

// out = h + v  (final block, no LN)
__global__ __launch_bounds__(256) void final_add(
    const float* __restrict__ h, const unsigned short* __restrict__ vb,
    float* __restrict__ out) {
    const size_t i = (size_t)blockIdx.x * 256 + threadIdx.x;
    float4 hv = ((const float4*)h)[i];
    ushort4 vv = ((const ushort4*)vb)[i];
    float4 o;
    o.x = hv.x + bf2f(vv.x); o.y = hv.y + bf2f(vv.y);
    o.z = hv.z + bf2f(vv.z); o.w = hv.w + bf2f(vv.w);
    ((float4*)out)[i] = o;
}

extern "C" void kernel_launch(void* const* d_in, const int* in_sizes, int n_in,
                              void* d_out, int out_size, void* d_ws, size_t ws_size,
                              hipStream_t stream) {
    const float* x      = (const float*)d_in[0];
    const int*   q      = (const int*)d_in[1];
    const float* scales = (const float*)d_in[2];
    const float* biases = (const float*)d_in[3];
    const float* la     = (const float*)d_in[4];
    const float* lb     = (const float*)d_in[5];
    const float* lng    = (const float*)d_in[6];
    const float* lnb    = (const float*)d_in[7];
    float* out = (float*)d_out;

    char* p = (char*)d_ws;
    unsigned short* weff = (unsigned short*)p; p += (size_t)NLAYERS * D * D * 2;
    unsigned short* xbA  = (unsigned short*)p; p += (size_t)BATCH * D * 2;
    unsigned short* xbB  = (unsigned short*)p; p += (size_t)BATCH * D * 2;
    float*          h    = (float*)p;

    prep_weights<<<NLAYERS * 16 * 4, 256, 0, stream>>>(q, scales, la, lb, weff);
    init_h<<<BATCH * D / 4 / 256, 256, 0, stream>>>(x, h, xbA);

    dim3 ggrid(D / 256, BATCH / 256);
    for (int blk = 0; blk < 6; ++blk) {
        const int li = 3 * blk;
        gemm256<<<ggrid, 512, 0, stream>>>(xbA, weff + (size_t)li * D * D,
                                           biases + (size_t)li * D, xbB, 0);
        gemm256<<<ggrid, 512, 0, stream>>>(xbB, weff + (size_t)(li + 1) * D * D,
                                           biases + (size_t)(li + 1) * D, xbA, 0);
        gemm256<<<ggrid, 512, 0, stream>>>(xbA, weff + (size_t)(li + 2) * D * D,
                                           biases + (size_t)(li + 2) * D, xbB, 1);
        if (blk < 5)
            resid_ln_v<<<BATCH, 256, 0, stream>>>(h, xbB, xbA,
                                                  lng + (size_t)blk * D, lnb + (size_t)blk * D);
        else
            final_add<<<BATCH * D / 4 / 256, 256, 0, stream>>>(h, xbB, out);
    }
}

// Round 7
// 902.353 us; speedup vs baseline: 1.1274x; 1.1274x over previous
//
#include <hip/hip_runtime.h>
#include <cstdint>
#include <cstddef>

#define D 1024
#define BATCH 16384
#define NLAYERS 18
#define RR 32

typedef __attribute__((ext_vector_type(8))) __bf16 bf16x8;
typedef __attribute__((ext_vector_type(4))) float f32x4;
typedef __attribute__((address_space(3))) void lds_void_t;
typedef __attribute__((address_space(1))) void gmem_void_t;

union bfpack { unsigned short us[8]; int4 v; };

__device__ __forceinline__ unsigned short f2bf(float f) {
    unsigned int b = __builtin_bit_cast(unsigned int, f);
    b += 0x7fffu + ((b >> 16) & 1u);
    return (unsigned short)(b >> 16);
}
__device__ __forceinline__ float bf2f(unsigned short u) {
    return __builtin_bit_cast(float, (unsigned int)u << 16);
}

// ---------------------------------------------------------------------------
// lora_gemm: loraB[li][o][i] = 4 * sum_r lb[li][o][r] * la[li][r][i], bf16.
// Rank-32 MFMA GEMM, 256x256 tile, 8 waves (2Mx4N), single K-step.
// lb staged f32->bf16 into lbs[256][40]; la staged TRANSPOSED into
// lat[256][40] (lat[i][r] = la[r][i]) so both operands are k-contiguous
// NT fragments (verified m89 mapping). Replaces R4's VALU phase-1
// (32-deep dependent FMA chains, latency-bound, 74us).
// ---------------------------------------------------------------------------
__global__ __launch_bounds__(512) void lora_gemm(
    const float* __restrict__ la, const float* __restrict__ lb,
    unsigned short* __restrict__ loraB) {
    __shared__ unsigned short lbs[256][40];   // 80B rows: 16B-aligned
    __shared__ unsigned short lat[256][40];
    const int b = blockIdx.x;                 // 18*16
    const int li = b >> 4;
    const int o0 = ((b >> 2) & 3) << 8;
    const int i0 = (b & 3) << 8;
    const int t = threadIdx.x;

    {   // lbs[row][r] = bf16(lb[li][o0+row][r]); thread t -> row t>>1, half t&1
        const int row = t >> 1, half = t & 1;
        const float* src = lb + ((size_t)(li * D) + o0 + row) * RR + half * 16;
        bfpack u[2];
#pragma unroll
        for (int j = 0; j < 2; ++j) {
            float4 v0 = ((const float4*)src)[2 * j];
            float4 v1 = ((const float4*)src)[2 * j + 1];
            u[j].us[0] = f2bf(v0.x); u[j].us[1] = f2bf(v0.y);
            u[j].us[2] = f2bf(v0.z); u[j].us[3] = f2bf(v0.w);
            u[j].us[4] = f2bf(v1.x); u[j].us[5] = f2bf(v1.y);
            u[j].us[6] = f2bf(v1.z); u[j].us[7] = f2bf(v1.w);
        }
        *(int4*)&lbs[row][half * 16] = u[0].v;
        *(int4*)&lbs[row][half * 16 + 8] = u[1].v;
    }
    {   // lat[col][r] = bf16(la[li][r][i0+col]); thread t -> col t>>1, rhalf t&1
        const int col = t >> 1, rhalf = t & 1;
#pragma unroll
        for (int rr = 0; rr < 16; ++rr) {
            const int r = rhalf * 16 + rr;
            lat[col][r] = f2bf(la[((size_t)li * RR + r) * D + i0 + col]);
        }
    }
    __syncthreads();

    const int wid = t >> 6, lane = t & 63;
    const int l15 = lane & 15, kgrp = lane >> 4;
    const int wrow = (wid >> 2) << 7;
    const int wcol = (wid & 3) << 6;

    bf16x8 a[8], bb[4];
#pragma unroll
    for (int f = 0; f < 8; ++f)
        a[f] = *(const bf16x8*)&lbs[wrow + (f << 4) + l15][kgrp << 3];
#pragma unroll
    for (int g = 0; g < 4; ++g)
        bb[g] = *(const bf16x8*)&lat[wcol + (g << 4) + l15][kgrp << 3];

    f32x4 acc[8][4];
#pragma unroll
    for (int i = 0; i < 8; ++i)
#pragma unroll
        for (int j = 0; j < 4; ++j) acc[i][j] = 0.0f;
#pragma unroll
    for (int mi = 0; mi < 8; ++mi)
#pragma unroll
        for (int ni = 0; ni < 4; ++ni)
            acc[mi][ni] = __builtin_amdgcn_mfma_f32_16x16x32_bf16(
                a[mi], bb[ni], acc[mi][ni], 0, 0, 0);

    // C/D: col = lane&15, row = kgrp*4 + r
    unsigned short* dst = loraB + (size_t)li * D * D;
#pragma unroll
    for (int mi = 0; mi < 8; ++mi) {
        const int row = o0 + wrow + (mi << 4) + (kgrp << 2);
#pragma unroll
        for (int ni = 0; ni < 4; ++ni) {
            const int col = i0 + wcol + (ni << 4) + l15;
#pragma unroll
            for (int r = 0; r < 4; ++r)
                dst[(size_t)(row + r) * D + col] = f2bf(4.0f * acc[mi][ni][r]);
        }
    }
}

// ---------------------------------------------------------------------------
// dequant: weff = (q/15*2-1)*scale + loraB   — pure streaming, coalesced.
// ---------------------------------------------------------------------------
__global__ __launch_bounds__(256) void dequant(
    const int* __restrict__ q, const float* __restrict__ scales,
    const unsigned short* __restrict__ loraB, unsigned short* __restrict__ weff) {
    const size_t n8 = (size_t)NLAYERS * D * D / 8;
    const float c = 2.0f / 15.0f;
    for (size_t i = (size_t)blockIdx.x * 256 + threadIdx.x; i < n8;
         i += (size_t)gridDim.x * 256) {
        const size_t base = i << 3;
        const int* qp = q + base;
        int4 q0 = ((const int4*)qp)[0], q1 = ((const int4*)qp)[1];
        bfpack lo;
        lo.v = *(const int4*)(loraB + base);
        const float s = scales[base >> 4];
        int qa[8] = {q0.x, q0.y, q0.z, q0.w, q1.x, q1.y, q1.z, q1.w};
        bfpack u;
#pragma unroll
        for (int j = 0; j < 8; ++j)
            u.us[j] = f2bf(((float)qa[j] * c - 1.0f) * s + bf2f(lo.us[j]));
        *(int4*)(weff + base) = u.v;
    }
}

// h = x (f32); xb = bf16(x)
__global__ __launch_bounds__(256) void init_h(const float* __restrict__ x,
                                              float* __restrict__ h,
                                              unsigned short* __restrict__ xb) {
    const size_t i = (size_t)blockIdx.x * 256 + threadIdx.x;
    float4 v = ((const float4*)x)[i];
    ((float4*)h)[i] = v;
    ushort4 u;
    u.x = f2bf(v.x); u.y = f2bf(v.y); u.z = f2bf(v.z); u.w = f2bf(v.w);
    ((ushort4*)xb)[i] = u;
}

// ---------------------------------------------------------------------------
// 256x256 tile GEMM, 8 waves (2Mx4N), 16x16x32 bf16 MFMA, BK=32 half-steps,
// 4-slot LDS ring, depth-3 counted-vmcnt pipeline (vmcnt(8) once per
// half-step, never 0 in main loop), XOR swizzle (both-sides), T5 setprio,
// T1 XCD-chunked blockIdx swizzle.  [R3-verified: ~36us/GEMM]
// mode 0: outb = bf16(relu(v));  mode 1: outb = bf16(v).
// ---------------------------------------------------------------------------
#define SBAR() do { asm volatile("" ::: "memory"); __builtin_amdgcn_s_barrier(); asm volatile("" ::: "memory"); } while (0)

__global__ __launch_bounds__(512, 2) void gemm256(
    const unsigned short* __restrict__ xb, const unsigned short* __restrict__ w,
    const float* __restrict__ bias,
    unsigned short* __restrict__ outb, int mode) {
    __shared__ __align__(16) char smem[131072];
    const int tid = threadIdx.x;
    const int wid = tid >> 6, lane = tid & 63;
    const int bid = blockIdx.x + (blockIdx.y << 2);
    const int xcd = bid & 7, slot = bid >> 3;
    const int m0 = ((xcd << 3) + (slot >> 2)) << 8;
    const int n0 = (slot & 3) << 8;
    const int l15 = lane & 15, kgrp = lane >> 4;
    const int wrow = (wid >> 2) << 7;   // 0 / 128
    const int wcol = (wid & 3) << 6;    // 0..192

    f32x4 acc[8][4];
#pragma unroll
    for (int i = 0; i < 8; ++i)
#pragma unroll
        for (int j = 0; j < 4; ++j) acc[i][j] = 0.0f;

#define STAGE_HALF(hs, i_)                                                     \
    do {                                                                       \
        const int k0_ = (hs) << 5;                                             \
        char* sA_ = smem + ((hs) & 3) * 32768;                                 \
        const int off_ = (i_) * 8192 + (tid << 4);                             \
        const int r_ = off_ >> 6;                                              \
        const int j_ = ((off_ >> 4) & 3) ^ ((r_ >> 1) & 3);                    \
        const unsigned short* ga_ = xb + (size_t)(m0 + r_) * D + k0_ + (j_ << 3); \
        const unsigned short* gb_ = w + (size_t)(n0 + r_) * D + k0_ + (j_ << 3);  \
        char* lA_ = sA_ + (i_) * 8192 + (wid << 10);                           \
        __builtin_amdgcn_global_load_lds((const gmem_void_t*)ga_, (lds_void_t*)lA_, 16, 0, 0);          \
        __builtin_amdgcn_global_load_lds((const gmem_void_t*)gb_, (lds_void_t*)(lA_ + 16384), 16, 0, 0); \
    } while (0)

    STAGE_HALF(0, 0); STAGE_HALF(0, 1);
    STAGE_HALF(1, 0); STAGE_HALF(1, 1);
    STAGE_HALF(2, 0); STAGE_HALF(2, 1);
    asm volatile("s_waitcnt vmcnt(8)" ::: "memory");   // slot 0 landed
    SBAR();

    for (int h = 0; h < 32; ++h) {
        const char* sA = smem + (h & 3) * 32768;
        const char* sB = sA + 16384;
        bf16x8 a[8], b[4];
        // ---- phase A: a0-3 + b0-3 reads, 2 stage loads, 16 MFMA ----
#pragma unroll
        for (int f = 0; f < 4; ++f) {
            const int r = wrow + (f << 4) + l15;
            a[f] = *(const bf16x8*)(sA + (r << 6) + ((kgrp ^ ((r >> 1) & 3)) << 4));
        }
#pragma unroll
        for (int g = 0; g < 4; ++g) {
            const int r = wcol + (g << 4) + l15;
            b[g] = *(const bf16x8*)(sB + (r << 6) + ((kgrp ^ ((r >> 1) & 3)) << 4));
        }
        if (h < 29) STAGE_HALF(h + 3, 0);
        SBAR();
        asm volatile("s_waitcnt lgkmcnt(0)" ::: "memory");
        __builtin_amdgcn_s_setprio(1);
#pragma unroll
        for (int mi = 0; mi < 4; ++mi)
#pragma unroll
            for (int ni = 0; ni < 4; ++ni)
                acc[mi][ni] = __builtin_amdgcn_mfma_f32_16x16x32_bf16(
                    a[mi], b[ni], acc[mi][ni], 0, 0, 0);
        __builtin_amdgcn_s_setprio(0);
        SBAR();
        // ---- phase B: a4-7 reads, 2 stage loads, vmcnt, 16 MFMA ----
#pragma unroll
        for (int f = 4; f < 8; ++f) {
            const int r = wrow + (f << 4) + l15;
            a[f] = *(const bf16x8*)(sA + (r << 6) + ((kgrp ^ ((r >> 1) & 3)) << 4));
        }
        if (h < 29) {
            STAGE_HALF(h + 3, 1);
            asm volatile("s_waitcnt vmcnt(8)" ::: "memory");  // stage h+1 landed
        } else if (h == 29) {
            asm volatile("s_waitcnt vmcnt(4)" ::: "memory");
        } else if (h == 30) {
            asm volatile("s_waitcnt vmcnt(0)" ::: "memory");
        }
        SBAR();
        asm volatile("s_waitcnt lgkmcnt(0)" ::: "memory");
        __builtin_amdgcn_s_setprio(1);
#pragma unroll
        for (int mi = 4; mi < 8; ++mi)
#pragma unroll
            for (int ni = 0; ni < 4; ++ni)
                acc[mi][ni] = __builtin_amdgcn_mfma_f32_16x16x32_bf16(
                    a[mi], b[ni], acc[mi][ni], 0, 0, 0);
        __builtin_amdgcn_s_setprio(0);
        SBAR();
    }

    // epilogue: C/D layout col = lane&15, row = (lane>>4)*4 + r
    const int crow = kgrp << 2;
    float bv[4];
#pragma unroll
    for (int ni = 0; ni < 4; ++ni) bv[ni] = bias[n0 + wcol + (ni << 4) + l15];
#pragma unroll
    for (int mi = 0; mi < 8; ++mi) {
        const int rbase = m0 + wrow + (mi << 4) + crow;
#pragma unroll
        for (int ni = 0; ni < 4; ++ni) {
            const int col = n0 + wcol + (ni << 4) + l15;
#pragma unroll
            for (int r = 0; r < 4; ++r) {
                float v = acc[mi][ni][r] + bv[ni];
                if (mode == 0) v = v > 0.0f ? v : 0.0f;
                outb[(size_t)(rbase + r) * D + col] = f2bf(v);
            }
        }
    }
}

// h = LN(h + v) in place; xb = bf16(result)
__global__ __launch_bounds__(256) void resid_ln_v(
    float* __restrict__ h, const unsigned short* __restrict__ vb,
    unsigned short* __restrict__ xb,
    const float* __restrict__ gamma, const float* __restrict__ beta) {
    const int row = blockIdx.x;
    const int t = threadIdx.x;
    float* hr = h + (size_t)row * D;
    float4 v = ((float4*)hr)[t];
    ushort4 vv = ((const ushort4*)(vb + (size_t)row * D))[t];
    v.x += bf2f(vv.x); v.y += bf2f(vv.y); v.z += bf2f(vv.z); v.w += bf2f(vv.w);
    float s = v.x + v.y + v.z + v.w;
    float s2 = v.x * v.x + v.y * v.y + v.z * v.z + v.w * v.w;
#pragma unroll
    for (int off = 32; off > 0; off >>= 1) {
        s += __shfl_down(s, off);
        s2 += __shfl_down(s2, off);
    }
    __shared__ float red[8];
    const int wid = t >> 6, lane = t & 63;
    if (lane == 0) { red[wid] = s; red[wid + 4] = s2; }
    __syncthreads();
    s = red[0] + red[1] + red[2] + red[3];
    s2 = red[4] + red[5] + red[6] + red[7];
    const float mu = s * (1.0f / D);
    const float var = s2 * (1.0f / D) - mu * mu;
    const float rs = rsqrtf(var + 1e-5f);
    float4 g = ((const float4*)gamma)[t];
    float4 b = ((const float4*)beta)[t];
    float4 o;
    o.x = (v.x - mu) * rs * g.x + b.x;
    o.y = (v.y - mu) * rs * g.y + b.y;
    o.z = (v.z - mu) * rs * g.z + b.z;
    o.w = (v.w - mu) * rs * g.w + b.w;
    ((float4*)hr)[t] = o;
    ushort4 u;
    u.x = f2bf(o.x); u.y = f2bf(o.y); u.z = f2bf(o.z); u.w = f2bf(o.w);
    ((ushort4*)(xb + (size_t)row * D))[t] = u;
}

// out = h + v  (final block, no LN)
__global__ __launch_bounds__(256) void final_add(
    const float* __restrict__ h, const unsigned short* __restrict__ vb,
    float* __restrict__ out) {
    const size_t i = (size_t)blockIdx.x * 256 + threadIdx.x;
    float4 hv = ((const float4*)h)[i];
    ushort4 vv = ((const ushort4*)vb)[i];
    float4 o;
    o.x = hv.x + bf2f(vv.x); o.y = hv.y + bf2f(vv.y);
    o.z = hv.z + bf2f(vv.z); o.w = hv.w + bf2f(vv.w);
    ((float4*)out)[i] = o;
}

extern "C" void kernel_launch(void* const* d_in, const int* in_sizes, int n_in,
                              void* d_out, int out_size, void* d_ws, size_t ws_size,
                              hipStream_t stream) {
    const float* x      = (const float*)d_in[0];
    const int*   q      = (const int*)d_in[1];
    const float* scales = (const float*)d_in[2];
    const float* biases = (const float*)d_in[3];
    const float* la     = (const float*)d_in[4];
    const float* lb     = (const float*)d_in[5];
    const float* lng    = (const float*)d_in[6];
    const float* lnb    = (const float*)d_in[7];
    float* out = (float*)d_out;

    char* p = (char*)d_ws;
    unsigned short* weff = (unsigned short*)p; p += (size_t)NLAYERS * D * D * 2;
    unsigned short* xbA  = (unsigned short*)p; p += (size_t)BATCH * D * 2;
    unsigned short* xbB  = (unsigned short*)p; p += (size_t)BATCH * D * 2;
    float*          h    = (float*)p;
    // loraB reuses the h region (dead until init_h): 37.75MB <= 67.1MB
    unsigned short* loraB = (unsigned short*)h;

    lora_gemm<<<NLAYERS * 16, 512, 0, stream>>>(la, lb, loraB);
    dequant<<<2048, 256, 0, stream>>>(q, scales, loraB, weff);
    init_h<<<BATCH * D / 4 / 256, 256, 0, stream>>>(x, h, xbA);

    dim3 ggrid(D / 256, BATCH / 256);
    for (int blk = 0; blk < 6; ++blk) {
        const int li = 3 * blk;
        gemm256<<<ggrid, 512, 0, stream>>>(xbA, weff + (size_t)li * D * D,
                                           biases + (size_t)li * D, xbB, 0);
        gemm256<<<ggrid, 512, 0, stream>>>(xbB, weff + (size_t)(li + 1) * D * D,
                                           biases + (size_t)(li + 1) * D, xbA, 0);
        gemm256<<<ggrid, 512, 0, stream>>>(xbA, weff + (size_t)(li + 2) * D * D,
                                           biases + (size_t)(li + 2) * D, xbB, 1);
        if (blk < 5)
            resid_ln_v<<<BATCH, 256, 0, stream>>>(h, xbB, xbA,
                                                  lng + (size_t)blk * D, lnb + (size_t)blk * D);
        else
            final_add<<<BATCH * D / 4 / 256, 256, 0, stream>>>(h, xbB, out);
    }
}

// Round 8
// 849.653 us; speedup vs baseline: 1.1973x; 1.0620x over previous
//
#include <hip/hip_runtime.h>
#include <cstdint>
#include <cstddef>

#define D 1024
#define BATCH 16384
#define NLAYERS 18
#define RR 32

typedef __attribute__((ext_vector_type(8))) __bf16 bf16x8;
typedef __attribute__((ext_vector_type(4))) float f32x4;
typedef __attribute__((address_space(3))) void lds_void_t;
typedef __attribute__((address_space(1))) void gmem_void_t;

union bfpack { unsigned short us[8]; int4 v; };

__device__ __forceinline__ unsigned short f2bf(float f) {
    unsigned int b = __builtin_bit_cast(unsigned int, f);
    b += 0x7fffu + ((b >> 16) & 1u);
    return (unsigned short)(b >> 16);
}
__device__ __forceinline__ float bf2f(unsigned short u) {
    return __builtin_bit_cast(float, (unsigned int)u << 16);
}

// ---------------------------------------------------------------------------
// lora_dequant: weff = (q/15*2-1)*scale + 4*(lb@la), bf16, fused.
// Block = 64 o-rows x 256 i-cols of one layer (grid 18*16*4), 4 waves.
// MFMA rank-32 for the LoRA tile -> out_s (LDS), then a fully-coalesced
// dequant pass reads q int4x2 + scales and writes weff int4. Eliminates
// the loraB global round-trip (R7: lora_gemm 10us + dequant 28us).
// ---------------------------------------------------------------------------
__global__ __launch_bounds__(256) void lora_dequant(
    const float* __restrict__ la, const float* __restrict__ lb,
    const int* __restrict__ q, const float* __restrict__ scales,
    unsigned short* __restrict__ weff) {
    __shared__ unsigned short lbs[64][40];     // [o][r] bf16, 80B rows
    __shared__ unsigned short lat[256][40];    // [i][r] bf16 (la transposed)
    __shared__ unsigned short out_s[64][264];  // lora tile, 528B rows
    const int b = blockIdx.x;                  // 18*16*4
    const int li = b >> 6;
    const int o0 = ((b >> 2) & 15) << 6;
    const int i0 = (b & 3) << 8;
    const int t = threadIdx.x;

    {   // lbs: 64x32 f32 -> bf16; thread t -> row t>>2, 8-col group t&3
        const int row = t >> 2, qt = t & 3;
        const float* src = lb + ((size_t)(li * D) + o0 + row) * RR + qt * 8;
        float4 v0 = ((const float4*)src)[0], v1 = ((const float4*)src)[1];
        bfpack u;
        u.us[0] = f2bf(v0.x); u.us[1] = f2bf(v0.y); u.us[2] = f2bf(v0.z); u.us[3] = f2bf(v0.w);
        u.us[4] = f2bf(v1.x); u.us[5] = f2bf(v1.y); u.us[6] = f2bf(v1.z); u.us[7] = f2bf(v1.w);
        *(int4*)&lbs[row][qt * 8] = u.v;
    }
    {   // lat[col][r] = bf16(la[li][r][i0+col]); coalesced across t per r
        const int col = t;
#pragma unroll 8
        for (int r = 0; r < 32; ++r)
            lat[col][r] = f2bf(la[((size_t)li * RR + r) * D + i0 + col]);
    }
    __syncthreads();

    {   // MFMA: wave w -> 32 o-rows x 128 i-cols; 2x8 16x16x32 frags
        const int wid = t >> 6, lane = t & 63;
        const int l15 = lane & 15, kgrp = lane >> 4;
        const int wrow = (wid >> 1) << 5;   // 0/32
        const int wcol = (wid & 1) << 7;    // 0/128
        bf16x8 a[2], bb[8];
#pragma unroll
        for (int f = 0; f < 2; ++f)
            a[f] = *(const bf16x8*)&lbs[wrow + (f << 4) + l15][kgrp << 3];
#pragma unroll
        for (int g = 0; g < 8; ++g)
            bb[g] = *(const bf16x8*)&lat[wcol + (g << 4) + l15][kgrp << 3];
        f32x4 acc[2][8];
#pragma unroll
        for (int i = 0; i < 2; ++i)
#pragma unroll
            for (int j = 0; j < 8; ++j) acc[i][j] = 0.0f;
#pragma unroll
        for (int mi = 0; mi < 2; ++mi)
#pragma unroll
            for (int ni = 0; ni < 8; ++ni)
                acc[mi][ni] = __builtin_amdgcn_mfma_f32_16x16x32_bf16(
                    a[mi], bb[ni], acc[mi][ni], 0, 0, 0);
        // C/D: col = l15, row = kgrp*4 + r
#pragma unroll
        for (int mi = 0; mi < 2; ++mi) {
            const int row = wrow + (mi << 4) + (kgrp << 2);
#pragma unroll
            for (int ni = 0; ni < 8; ++ni) {
                const int col = wcol + (ni << 4) + l15;
#pragma unroll
                for (int r = 0; r < 4; ++r)
                    out_s[row + r][col] = f2bf(4.0f * acc[mi][ni][r]);
            }
        }
    }
    __syncthreads();

    // coalesced dequant: 8 passes, thread -> (row idx>>5, 8-col grp (idx&31)*8)
    const float c = 2.0f / 15.0f;
#pragma unroll 1
    for (int iter = 0; iter < 8; ++iter) {
        const int idx = (iter << 8) + t;
        const int row = idx >> 5, c8 = (idx & 31) << 3;
        const size_t grow = (size_t)li * D + o0 + row;
        const int col = i0 + c8;
        const float s = scales[grow * (D / 16) + (col >> 4)];
        const int* qp = q + grow * D + col;
        int4 q0 = ((const int4*)qp)[0], q1 = ((const int4*)qp)[1];
        bfpack lo;
        lo.v = *(const int4*)&out_s[row][c8];
        int qa[8] = {q0.x, q0.y, q0.z, q0.w, q1.x, q1.y, q1.z, q1.w};
        bfpack u;
#pragma unroll
        for (int j = 0; j < 8; ++j)
            u.us[j] = f2bf(((float)qa[j] * c - 1.0f) * s + bf2f(lo.us[j]));
        *(int4*)(weff + grow * D + col) = u.v;
    }
}

// xb = bf16(x)  — the residual stream lives in bf16 only
__global__ __launch_bounds__(256) void init_xb(const float* __restrict__ x,
                                               unsigned short* __restrict__ xb) {
    const size_t i = (size_t)blockIdx.x * 256 + threadIdx.x;
    float4 v = ((const float4*)x)[i];
    ushort4 u;
    u.x = f2bf(v.x); u.y = f2bf(v.y); u.z = f2bf(v.z); u.w = f2bf(v.w);
    ((ushort4*)xb)[i] = u;
}

// ---------------------------------------------------------------------------
// 256x256 tile GEMM, 8 waves (2Mx4N), 16x16x32 bf16 MFMA, BK=32 half-steps,
// 4-slot LDS ring, depth-3 counted-vmcnt pipeline (vmcnt(8) once per
// half-step, never 0 in main loop), XOR swizzle (both-sides), T5 setprio,
// T1 XCD-chunked blockIdx swizzle.  [R3/R7-verified: ~37us avg, ~930 TF]
// mode 0: outb = bf16(relu(v));  mode 1: outb = bf16(v).
// ---------------------------------------------------------------------------
#define SBAR() do { asm volatile("" ::: "memory"); __builtin_amdgcn_s_barrier(); asm volatile("" ::: "memory"); } while (0)

__global__ __launch_bounds__(512, 2) void gemm256(
    const unsigned short* __restrict__ xb, const unsigned short* __restrict__ w,
    const float* __restrict__ bias,
    unsigned short* __restrict__ outb, int mode) {
    __shared__ __align__(16) char smem[131072];
    const int tid = threadIdx.x;
    const int wid = tid >> 6, lane = tid & 63;
    const int bid = blockIdx.x + (blockIdx.y << 2);
    const int xcd = bid & 7, slot = bid >> 3;
    const int m0 = ((xcd << 3) + (slot >> 2)) << 8;
    const int n0 = (slot & 3) << 8;
    const int l15 = lane & 15, kgrp = lane >> 4;
    const int wrow = (wid >> 2) << 7;   // 0 / 128
    const int wcol = (wid & 3) << 6;    // 0..192

    f32x4 acc[8][4];
#pragma unroll
    for (int i = 0; i < 8; ++i)
#pragma unroll
        for (int j = 0; j < 4; ++j) acc[i][j] = 0.0f;

#define STAGE_HALF(hs, i_)                                                     \
    do {                                                                       \
        const int k0_ = (hs) << 5;                                             \
        char* sA_ = smem + ((hs) & 3) * 32768;                                 \
        const int off_ = (i_) * 8192 + (tid << 4);                             \
        const int r_ = off_ >> 6;                                              \
        const int j_ = ((off_ >> 4) & 3) ^ ((r_ >> 1) & 3);                    \
        const unsigned short* ga_ = xb + (size_t)(m0 + r_) * D + k0_ + (j_ << 3); \
        const unsigned short* gb_ = w + (size_t)(n0 + r_) * D + k0_ + (j_ << 3);  \
        char* lA_ = sA_ + (i_) * 8192 + (wid << 10);                           \
        __builtin_amdgcn_global_load_lds((const gmem_void_t*)ga_, (lds_void_t*)lA_, 16, 0, 0);          \
        __builtin_amdgcn_global_load_lds((const gmem_void_t*)gb_, (lds_void_t*)(lA_ + 16384), 16, 0, 0); \
    } while (0)

    STAGE_HALF(0, 0); STAGE_HALF(0, 1);
    STAGE_HALF(1, 0); STAGE_HALF(1, 1);
    STAGE_HALF(2, 0); STAGE_HALF(2, 1);
    asm volatile("s_waitcnt vmcnt(8)" ::: "memory");   // slot 0 landed
    SBAR();

    for (int h = 0; h < 32; ++h) {
        const char* sA = smem + (h & 3) * 32768;
        const char* sB = sA + 16384;
        bf16x8 a[8], b[4];
        // ---- phase A: a0-3 + b0-3 reads, 2 stage loads, 16 MFMA ----
#pragma unroll
        for (int f = 0; f < 4; ++f) {
            const int r = wrow + (f << 4) + l15;
            a[f] = *(const bf16x8*)(sA + (r << 6) + ((kgrp ^ ((r >> 1) & 3)) << 4));
        }
#pragma unroll
        for (int g = 0; g < 4; ++g) {
            const int r = wcol + (g << 4) + l15;
            b[g] = *(const bf16x8*)(sB + (r << 6) + ((kgrp ^ ((r >> 1) & 3)) << 4));
        }
        if (h < 29) STAGE_HALF(h + 3, 0);
        SBAR();
        asm volatile("s_waitcnt lgkmcnt(0)" ::: "memory");
        __builtin_amdgcn_s_setprio(1);
#pragma unroll
        for (int mi = 0; mi < 4; ++mi)
#pragma unroll
            for (int ni = 0; ni < 4; ++ni)
                acc[mi][ni] = __builtin_amdgcn_mfma_f32_16x16x32_bf16(
                    a[mi], b[ni], acc[mi][ni], 0, 0, 0);
        __builtin_amdgcn_s_setprio(0);
        SBAR();
        // ---- phase B: a4-7 reads, 2 stage loads, vmcnt, 16 MFMA ----
#pragma unroll
        for (int f = 4; f < 8; ++f) {
            const int r = wrow + (f << 4) + l15;
            a[f] = *(const bf16x8*)(sA + (r << 6) + ((kgrp ^ ((r >> 1) & 3)) << 4));
        }
        if (h < 29) {
            STAGE_HALF(h + 3, 1);
            asm volatile("s_waitcnt vmcnt(8)" ::: "memory");  // stage h+1 landed
        } else if (h == 29) {
            asm volatile("s_waitcnt vmcnt(4)" ::: "memory");
        } else if (h == 30) {
            asm volatile("s_waitcnt vmcnt(0)" ::: "memory");
        }
        SBAR();
        asm volatile("s_waitcnt lgkmcnt(0)" ::: "memory");
        __builtin_amdgcn_s_setprio(1);
#pragma unroll
        for (int mi = 4; mi < 8; ++mi)
#pragma unroll
            for (int ni = 0; ni < 4; ++ni)
                acc[mi][ni] = __builtin_amdgcn_mfma_f32_16x16x32_bf16(
                    a[mi], b[ni], acc[mi][ni], 0, 0, 0);
        __builtin_amdgcn_s_setprio(0);
        SBAR();
    }

    // epilogue: C/D layout col = lane&15, row = (lane>>4)*4 + r
    const int crow = kgrp << 2;
    float bv[4];
#pragma unroll
    for (int ni = 0; ni < 4; ++ni) bv[ni] = bias[n0 + wcol + (ni << 4) + l15];
#pragma unroll
    for (int mi = 0; mi < 8; ++mi) {
        const int rbase = m0 + wrow + (mi << 4) + crow;
#pragma unroll
        for (int ni = 0; ni < 4; ++ni) {
            const int col = n0 + wcol + (ni << 4) + l15;
#pragma unroll
            for (int r = 0; r < 4; ++r) {
                float v = acc[mi][ni][r] + bv[ni];
                if (mode == 0) v = v > 0.0f ? v : 0.0f;
                outb[(size_t)(rbase + r) * D + col] = f2bf(v);
            }
        }
    }
}

// hb = bf16(LN(hb + vb)) in place (bf16 residual stream, 96MB vs 192MB)
__global__ __launch_bounds__(256) void resid_ln_b(
    unsigned short* __restrict__ hb, const unsigned short* __restrict__ vb,
    const float* __restrict__ gamma, const float* __restrict__ beta) {
    const int row = blockIdx.x;
    const int t = threadIdx.x;
    unsigned short* hr = hb + (size_t)row * D;
    ushort4 hv = ((const ushort4*)hr)[t];
    ushort4 vv = ((const ushort4*)(vb + (size_t)row * D))[t];
    float4 v;
    v.x = bf2f(hv.x) + bf2f(vv.x); v.y = bf2f(hv.y) + bf2f(vv.y);
    v.z = bf2f(hv.z) + bf2f(vv.z); v.w = bf2f(hv.w) + bf2f(vv.w);
    float s = v.x + v.y + v.z + v.w;
    float s2 = v.x * v.x + v.y * v.y + v.z * v.z + v.w * v.w;
#pragma unroll
    for (int off = 32; off > 0; off >>= 1) {
        s += __shfl_down(s, off);
        s2 += __shfl_down(s2, off);
    }
    __shared__ float red[8];
    const int wid = t >> 6, lane = t & 63;
    if (lane == 0) { red[wid] = s; red[wid + 4] = s2; }
    __syncthreads();
    s = red[0] + red[1] + red[2] + red[3];
    s2 = red[4] + red[5] + red[6] + red[7];
    const float mu = s * (1.0f / D);
    const float var = s2 * (1.0f / D) - mu * mu;
    const float rs = rsqrtf(var + 1e-5f);
    float4 g = ((const float4*)gamma)[t];
    float4 b = ((const float4*)beta)[t];
    ushort4 u;
    u.x = f2bf((v.x - mu) * rs * g.x + b.x);
    u.y = f2bf((v.y - mu) * rs * g.y + b.y);
    u.z = f2bf((v.z - mu) * rs * g.z + b.z);
    u.w = f2bf((v.w - mu) * rs * g.w + b.w);
    ((ushort4*)hr)[t] = u;
}

// out = h + v  (final block, no LN; h,v bf16 -> f32 out)
__global__ __launch_bounds__(256) void final_add(
    const unsigned short* __restrict__ hb, const unsigned short* __restrict__ vb,
    float* __restrict__ out) {
    const size_t i = (size_t)blockIdx.x * 256 + threadIdx.x;
    ushort4 hv = ((const ushort4*)hb)[i];
    ushort4 vv = ((const ushort4*)vb)[i];
    float4 o;
    o.x = bf2f(hv.x) + bf2f(vv.x); o.y = bf2f(hv.y) + bf2f(vv.y);
    o.z = bf2f(hv.z) + bf2f(vv.z); o.w = bf2f(hv.w) + bf2f(vv.w);
    ((float4*)out)[i] = o;
}

extern "C" void kernel_launch(void* const* d_in, const int* in_sizes, int n_in,
                              void* d_out, int out_size, void* d_ws, size_t ws_size,
                              hipStream_t stream) {
    const float* x      = (const float*)d_in[0];
    const int*   q      = (const int*)d_in[1];
    const float* scales = (const float*)d_in[2];
    const float* biases = (const float*)d_in[3];
    const float* la     = (const float*)d_in[4];
    const float* lb     = (const float*)d_in[5];
    const float* lng    = (const float*)d_in[6];
    const float* lnb    = (const float*)d_in[7];
    float* out = (float*)d_out;

    char* p = (char*)d_ws;
    unsigned short* weff = (unsigned short*)p; p += (size_t)NLAYERS * D * D * 2;  // 37.75MB
    unsigned short* xbA  = (unsigned short*)p; p += (size_t)BATCH * D * 2;        // 33.55MB (residual stream)
    unsigned short* xbB  = (unsigned short*)p; p += (size_t)BATCH * D * 2;        // 33.55MB
    unsigned short* xbC  = (unsigned short*)p;                                    // 33.55MB

    lora_dequant<<<NLAYERS * 16 * 4, 256, 0, stream>>>(la, lb, q, scales, weff);
    init_xb<<<BATCH * D / 4 / 256, 256, 0, stream>>>(x, xbA);

    dim3 ggrid(D / 256, BATCH / 256);
    for (int blk = 0; blk < 6; ++blk) {
        const int li = 3 * blk;
        // xbA = residual stream (must survive); ping-pong through xbB/xbC
        gemm256<<<ggrid, 512, 0, stream>>>(xbA, weff + (size_t)li * D * D,
                                           biases + (size_t)li * D, xbB, 0);
        gemm256<<<ggrid, 512, 0, stream>>>(xbB, weff + (size_t)(li + 1) * D * D,
                                           biases + (size_t)(li + 1) * D, xbC, 0);
        gemm256<<<ggrid, 512, 0, stream>>>(xbC, weff + (size_t)(li + 2) * D * D,
                                           biases + (size_t)(li + 2) * D, xbB, 1);
        if (blk < 5)
            resid_ln_b<<<BATCH, 256, 0, stream>>>(xbA, xbB,
                                                  lng + (size_t)blk * D, lnb + (size_t)blk * D);
        else
            final_add<<<BATCH * D / 4 / 256, 256, 0, stream>>>(xbA, xbB, out);
    }
}